// Round 1
// baseline (227.507 us; speedup 1.0000x reference)
//
#include <hip/hip_runtime.h>
#include <math.h>

// Problem constants (fixed by reference setup_inputs)
constexpr int Nn = 2, Hh = 8, Ll = 2048, Dd = 64;
constexpr int S  = Nn * Hh;      // 16 independent (n,h) sequences
constexpr int C  = 64;           // chunk length along L
constexpr int NC = Ll / C;       // 32 chunks per sequence
constexpr int SC = S * NC;       // 512 chunk-blocks total

#define EPSF 1e-6f

__device__ __forceinline__ float sigf(float x) { return 1.0f / (1.0f + expf(-x)); }

__device__ __forceinline__ float waveRed(float v) {
#pragma unroll
    for (int off = 32; off > 0; off >>= 1) v += __shfl_xor(v, off, 64);
    return v;
}

__device__ __forceinline__ int gidx(int n, int l, int h, int d) {
    return ((n * Ll + l) * Hh + h) * Dd + d;
}

// K1: per-chunk sums of sigmoid(k), sigmoid(q).  grid=SC, block=64
__global__ void k_chunksums(const float* __restrict__ Q, const float* __restrict__ K,
                            float* __restrict__ SK, float* __restrict__ SQ) {
    int b = blockIdx.x, s = b / NC, c = b % NC;
    int n = s / Hh, h = s % Hh, d = threadIdx.x;
    float sk = 0.f, sq = 0.f;
    for (int i = 0; i < C; i++) {
        int l = c * C + i, id = gidx(n, l, h, d);
        sk += sigf(K[id]);
        sq += sigf(Q[id]);
    }
    SK[b * Dd + d] = sk;
    SQ[b * Dd + d] = sq;
}

// K2/K4: in-place exclusive prefix over chunks for two [S,NC,D] arrays. grid=S, block=64
__global__ void k_prefixAB(float* __restrict__ A, float* __restrict__ B) {
    int s = blockIdx.x, d = threadIdx.x;
    float ra = 0.f, rb = 0.f;
    for (int c = 0; c < NC; c++) {
        int o = (s * NC + c) * Dd + d;
        float ta = A[o], tb = B[o];
        A[o] = ra; B[o] = rb;
        ra += ta; rb += tb;
    }
}

// K3: walk chunk with running cumsum(k),cumsum(q); emit si,so (incl. normal) and
//     chunk sums of k*so, q*si.  grid=SC, block=64
__global__ void k_pass1(const float* __restrict__ Q, const float* __restrict__ K,
                        const float* __restrict__ SK, const float* __restrict__ SQ,
                        float* __restrict__ SKso, float* __restrict__ SQsi,
                        float* __restrict__ si, float* __restrict__ so) {
    int b = blockIdx.x, s = b / NC, c = b % NC;
    int n = s / Hh, h = s % Hh, d = threadIdx.x;
    float Ck = SK[b * Dd + d], Cq = SQ[b * Dd + d];
    float aK = 0.f, aQ = 0.f;
    for (int i = 0; i < C; i++) {
        int l = c * C + i, id = gidx(n, l, h, d);
        float sk = sigf(K[id]), sq = sigf(Q[id]);
        Ck += sk; Cq += sq;
        float d1 = waveRed((sq + EPSF) * (Ck + EPSF));
        float d2 = waveRed((sk + EPSF) * (Cq + EPSF));
        float nf = (float)(l + 1);
        float siF = nf / d1, soF = nf / d2;
        if (d == 0) { si[s * Ll + l] = siF; so[s * Ll + l] = soF; }
        aK += sk * soF;
        aQ += sq * siF;
    }
    SKso[b * Dd + d] = aK;
    SQsi[b * Dd + d] = aQ;
}

// K5: walk chunk with running cumsum(k*so), cumsum(q*si); emit sink_allocation,
//     e=exp(clip(conserved_source)), chunk-local inclusive cumsum of e, chunk total.
//     grid=SC, block=64
__global__ void k_pass2(const float* __restrict__ Q, const float* __restrict__ K,
                        const float* __restrict__ SKso, const float* __restrict__ SQsi,
                        const float* __restrict__ si, const float* __restrict__ so,
                        float* __restrict__ sal, float* __restrict__ ecs,
                        float* __restrict__ ecum, float* __restrict__ Tcs) {
    int b = blockIdx.x, s = b / NC, c = b % NC;
    int n = s / Hh, h = s % Hh, d = threadIdx.x;
    float Ckso = SKso[b * Dd + d], Cqsi = SQsi[b * Dd + d];
    float run = 0.f;
    for (int i = 0; i < C; i++) {
        int l = c * C + i, id = gidx(n, l, h, d);
        float sk = sigf(K[id]), sq = sigf(Q[id]);
        float soF = so[s * Ll + l], siF = si[s * Ll + l];
        Ckso += sk * soF;
        Cqsi += sq * siF;
        float nf = (float)(l + 1);
        float cs  = waveRed((sq + EPSF) * (Ckso + EPSF)) / nf;   // conserved_sink
        float csr = waveRed((sk + EPSF) * (Cqsi + EPSF)) / nf;   // conserved_source
        csr = fminf(fmaxf(csr, -1.f), 1.f);
        float ev = expf(csr);
        run += ev;
        if (d == 0) {
            sal[s * Ll + l]  = 1.0f / (1.0f + expf(-cs));
            ecs[s * Ll + l]  = ev;
            ecum[s * Ll + l] = run;   // inclusive, chunk-local
        }
    }
    if (d == 0) Tcs[b] = run;
}

// K6: exclusive prefix of chunk totals of e.  grid=S, block=64 (thread 0 works)
__global__ void k_prefixT(const float* __restrict__ Tcs, float* __restrict__ Pcs) {
    int s = blockIdx.x;
    if (threadIdx.x == 0) {
        float r = 0.f;
        for (int c = 0; c < NC; c++) {
            Pcs[s * NC + c] = r;
            r += Tcs[s * NC + c];
        }
    }
}

// K7: per-chunk KV sums: KV_c[d][m] = sum_l k[l][d] * (v[l][m]*scomp[l]).
//     grid=SC, block=256 (each thread owns a 4x4 tile of the 64x64 matrix)
__global__ __launch_bounds__(256) void k_chunkKV(const float* __restrict__ K,
                                                 const float* __restrict__ V,
                                                 const float* __restrict__ ecs,
                                                 const float* __restrict__ ecum,
                                                 const float* __restrict__ Pcs,
                                                 float* __restrict__ KV) {
    __shared__ float lk[C][Dd];
    __shared__ float lvs[C][Dd];
    __shared__ float lsc[C];
    int b = blockIdx.x, s = b / NC, c = b % NC;
    int n = s / Hh, h = s % Hh, t = threadIdx.x;
    if (t < C) {
        int l = c * C + t;
        lsc[t] = ecs[s * Ll + l] / (Pcs[b] + ecum[s * Ll + l]) * (float)(l + 1);
    }
    __syncthreads();
    for (int j = 0; j < C * Dd / 256; j++) {
        int flat = t + j * 256, i = flat >> 6, d = flat & 63;
        int l = c * C + i, id = gidx(n, l, h, d);
        lk[i][d]  = sigf(K[id]);
        lvs[i][d] = V[id] * lsc[i];
    }
    __syncthreads();
    int tx = t & 15, ty = t >> 4;
    int m0 = tx * 4, d0 = ty * 4;
    float acc[4][4] = {};
    for (int i = 0; i < C; i++) {
        float4 k4 = *(const float4*)&lk[i][d0];
        float4 v4 = *(const float4*)&lvs[i][m0];
        float kk[4] = {k4.x, k4.y, k4.z, k4.w};
        float vv[4] = {v4.x, v4.y, v4.z, v4.w};
#pragma unroll
        for (int r = 0; r < 4; r++)
#pragma unroll
            for (int cc = 0; cc < 4; cc++) acc[r][cc] += kk[r] * vv[cc];
    }
    float* dst = &KV[(size_t)b * Dd * Dd];
#pragma unroll
    for (int r = 0; r < 4; r++) {
        float4 o = {acc[r][0], acc[r][1], acc[r][2], acc[r][3]};
        *(float4*)&dst[(d0 + r) * Dd + m0] = o;
    }
}

// K8: in-place exclusive prefix of KV over chunks. grid=S*16, block=256
__global__ void k_prefixKV(float* __restrict__ KV) {
    int bx = blockIdx.x, s = bx >> 4, sub = bx & 15;
    int e0 = sub * 256 + threadIdx.x;
    float r = 0.f;
    for (int c = 0; c < NC; c++) {
        size_t a = (size_t)(s * NC + c) * (Dd * Dd) + e0;
        float t = KV[a];
        KV[a] = r;
        r += t;
    }
}

// K9: final causal pass. grid=SC, block=64 (lane m owns KV column m in registers)
__global__ __launch_bounds__(64) void k_final(const float* __restrict__ Q,
                                              const float* __restrict__ K,
                                              const float* __restrict__ V,
                                              const float* __restrict__ si,
                                              const float* __restrict__ sal,
                                              const float* __restrict__ ecs,
                                              const float* __restrict__ ecum,
                                              const float* __restrict__ Pcs,
                                              const float* __restrict__ KV,
                                              float* __restrict__ Out) {
    __shared__ float lk[C][Dd];
    __shared__ float lqs[C][Dd];
    __shared__ float lvs[C][Dd];
    int b = blockIdx.x, s = b / NC, c = b % NC;
    int n = s / Hh, h = s % Hh, m = threadIdx.x;

    float kvr[Dd];
    const float* kvp = &KV[(size_t)b * Dd * Dd];
#pragma unroll
    for (int dd = 0; dd < Dd; dd++) kvr[dd] = kvp[dd * Dd + m];

    float pcs = Pcs[b];
    for (int i = 0; i < C; i++) {
        int l = c * C + i, id = gidx(n, l, h, m);
        float sc  = ecs[s * Ll + l] / (pcs + ecum[s * Ll + l]) * (float)(l + 1);
        float sir = si[s * Ll + l] / (float)(l + 1);
        lk[i][m]  = sigf(K[id]);
        lqs[i][m] = sigf(Q[id]) * sir;
        lvs[i][m] = V[id] * sc;
    }
    __syncthreads();

    for (int i = 0; i < C; i++) {
        int l = c * C + i;
        float vsm = lvs[i][m];
        float out = 0.f;
#pragma unroll
        for (int dd = 0; dd < Dd; dd += 4) {
            float4 k4 = *(const float4*)&lk[i][dd];
            float4 q4 = *(const float4*)&lqs[i][dd];
            kvr[dd + 0] += k4.x * vsm; out += q4.x * kvr[dd + 0];
            kvr[dd + 1] += k4.y * vsm; out += q4.y * kvr[dd + 1];
            kvr[dd + 2] += k4.z * vsm; out += q4.z * kvr[dd + 2];
            kvr[dd + 3] += k4.w * vsm; out += q4.w * kvr[dd + 3];
        }
        float sa = sal[s * Ll + l];
        Out[gidx(n, l, h, m)] = out * sa;
    }
}

extern "C" void kernel_launch(void* const* d_in, const int* in_sizes, int n_in,
                              void* d_out, int out_size, void* d_ws, size_t ws_size,
                              hipStream_t stream) {
    const float* Q = (const float*)d_in[0];
    const float* K = (const float*)d_in[1];
    const float* V = (const float*)d_in[2];
    float* Out = (float*)d_out;

    float* ws   = (float*)d_ws;
    float* SK   = ws;                 // SC*Dd
    float* SQ   = SK   + SC * Dd;     // SC*Dd
    float* SKso = SQ   + SC * Dd;     // SC*Dd
    float* SQsi = SKso + SC * Dd;     // SC*Dd
    float* si   = SQsi + SC * Dd;     // S*Ll
    float* so   = si   + S * Ll;      // S*Ll
    float* sal  = so   + S * Ll;      // S*Ll
    float* ecs  = sal  + S * Ll;      // S*Ll
    float* ecum = ecs  + S * Ll;      // S*Ll
    float* Tcs  = ecum + S * Ll;      // SC
    float* Pcs  = Tcs  + SC;          // SC
    float* KV   = Pcs  + SC;          // SC*Dd*Dd  (total ~9.6 MB)

    k_chunksums<<<SC, 64, 0, stream>>>(Q, K, SK, SQ);
    k_prefixAB<<<S, 64, 0, stream>>>(SK, SQ);
    k_pass1<<<SC, 64, 0, stream>>>(Q, K, SK, SQ, SKso, SQsi, si, so);
    k_prefixAB<<<S, 64, 0, stream>>>(SKso, SQsi);
    k_pass2<<<SC, 64, 0, stream>>>(Q, K, SKso, SQsi, si, so, sal, ecs, ecum, Tcs);
    k_prefixT<<<S, 64, 0, stream>>>(Tcs, Pcs);
    k_chunkKV<<<SC, 256, 0, stream>>>(K, V, ecs, ecum, Pcs, KV);
    k_prefixKV<<<S * 16, 256, 0, stream>>>(KV);
    k_final<<<SC, 64, 0, stream>>>(Q, K, V, si, sal, ecs, ecum, Pcs, KV, Out);
}

// Round 2
// 150.357 us; speedup vs baseline: 1.5131x; 1.5131x over previous
//
#include <hip/hip_runtime.h>
#include <math.h>

// Problem constants (fixed by reference setup_inputs)
constexpr int Nn = 2, Hh = 8, Ll = 2048, Dd = 64;
constexpr int S  = Nn * Hh;      // 16 independent (n,h) sequences
constexpr int C  = 64;           // chunk length along L
constexpr int NC = Ll / C;       // 32 chunks per sequence
constexpr int SC = S * NC;       // 512 chunk-blocks total

constexpr int SRT = 68;          // LDS stride for transposed operand arrays (float4-aligned, low-conflict)
constexpr int SRP = 65;          // LDS stride for the score matrix P (scalar access, conflict-free scans)

#define EPSF 1e-6f

__device__ __forceinline__ float sigf(float x) { return 1.0f / (1.0f + expf(-x)); }

__device__ __forceinline__ int gidx(int n, int l, int h, int d) {
    return ((n * Ll + l) * Hh + h) * Dd + d;
}

// K1: per-chunk sums of sigmoid(k), sigmoid(q).  grid=SC, block=64
__global__ void k_chunksums(const float* __restrict__ Q, const float* __restrict__ K,
                            float* __restrict__ SK, float* __restrict__ SQ) {
    int b = blockIdx.x, s = b / NC, c = b % NC;
    int n = s / Hh, h = s % Hh, d = threadIdx.x;
    float sk = 0.f, sq = 0.f;
    for (int i = 0; i < C; i++) {
        int l = c * C + i, id = gidx(n, l, h, d);
        sk += sigf(K[id]);
        sq += sigf(Q[id]);
    }
    SK[b * Dd + d] = sk;
    SQ[b * Dd + d] = sq;
}

// K2/K4: in-place exclusive prefix over chunks for two [S,NC,D] arrays. grid=S, block=64
__global__ void k_prefixAB(float* __restrict__ A, float* __restrict__ B) {
    int s = blockIdx.x, d = threadIdx.x;
    float ra = 0.f, rb = 0.f;
    for (int c = 0; c < NC; c++) {
        int o = (s * NC + c) * Dd + d;
        float ta = A[o], tb = B[o];
        A[o] = ra; B[o] = rb;
        ra += ta; rb += tb;
    }
}

// K3: matmul-form pass1. One 256-thread block per chunk.
//  P[i][j] = sum_d sq_i[d]*sk_j[d]; then causal row/col sums give si/so.
__global__ __launch_bounds__(256) void k_pass1mm(const float* __restrict__ Q,
                                                 const float* __restrict__ K,
                                                 const float* __restrict__ SK,
                                                 const float* __restrict__ SQ,
                                                 float* __restrict__ SKso,
                                                 float* __restrict__ SQsi,
                                                 float* __restrict__ si,
                                                 float* __restrict__ so) {
    __shared__ float sqT[Dd * SRT];   // sqT[d*SRT + i] = sigmoid(q_i[d])
    __shared__ float skT[Dd * SRT];
    __shared__ float P[C * SRP];      // P[i*SRP + j]
    __shared__ float colK[C], colQ[C], pk[Dd], pq[Dd], lsi[C], lso[C];
    int b = blockIdx.x, s = b / NC, c = b % NC;
    int n = s / Hh, h = s % Hh, t = threadIdx.x;

    // stage (float4 global reads, transposed scalar LDS writes)
#pragma unroll
    for (int j = 0; j < 4; j++) {
        int flat = 4 * t + 1024 * j, i = flat >> 6, d0 = flat & 63;
        int id = gidx(n, c * C + i, h, d0);
        float4 q4 = *(const float4*)&Q[id];
        float4 k4 = *(const float4*)&K[id];
        sqT[(d0 + 0) * SRT + i] = sigf(q4.x);
        sqT[(d0 + 1) * SRT + i] = sigf(q4.y);
        sqT[(d0 + 2) * SRT + i] = sigf(q4.z);
        sqT[(d0 + 3) * SRT + i] = sigf(q4.w);
        skT[(d0 + 0) * SRT + i] = sigf(k4.x);
        skT[(d0 + 1) * SRT + i] = sigf(k4.y);
        skT[(d0 + 2) * SRT + i] = sigf(k4.z);
        skT[(d0 + 3) * SRT + i] = sigf(k4.w);
    }
    if (t < Dd) { pk[t] = SK[b * Dd + t]; pq[t] = SQ[b * Dd + t]; }
    __syncthreads();

    // P tiles: thread (tx,ty) owns rows i0..i0+3, cols j0..j0+3
    int tx = t & 15, ty = t >> 4, i0 = 4 * ty, j0 = 4 * tx;
    float acc[4][4] = {};
    for (int d = 0; d < Dd; d++) {
        float4 a = *(const float4*)&sqT[d * SRT + i0];
        float4 bb = *(const float4*)&skT[d * SRT + j0];
        float av[4] = {a.x, a.y, a.z, a.w}, bv[4] = {bb.x, bb.y, bb.z, bb.w};
#pragma unroll
        for (int r = 0; r < 4; r++)
#pragma unroll
            for (int cc = 0; cc < 4; cc++) acc[r][cc] += av[r] * bv[cc];
    }
#pragma unroll
    for (int r = 0; r < 4; r++)
#pragma unroll
        for (int cc = 0; cc < 4; cc++) P[(i0 + r) * SRP + (j0 + cc)] = acc[r][cc];
    __syncthreads();

    if (t < C) {
        float ck = 0.f, cq = 0.f;
        for (int d = 0; d < Dd; d++) { ck += skT[d * SRT + t]; cq += sqT[d * SRT + t]; }
        colK[t] = ck; colQ[t] = cq;
    }
    __syncthreads();

    if (t < C) {
        int i = t, l = c * C + i;
        float r1 = 0.f, r2 = 0.f;
        for (int j = 0; j <= i; j++) {
            r1 += P[i * SRP + j] + EPSF * colK[j];
            r2 += P[j * SRP + i] + EPSF * colQ[j];
        }
        float b1 = 0.f, b2 = 0.f;
        for (int d = 0; d < Dd; d++) {
            b1 += (sqT[d * SRT + i] + EPSF) * (pk[d] + EPSF);
            b2 += (skT[d * SRT + i] + EPSF) * (pq[d] + EPSF);
        }
        float nf = (float)(l + 1);
        float siF = nf / (b1 + r1), soF = nf / (b2 + r2);
        si[s * Ll + l] = siF; so[s * Ll + l] = soF;
        lsi[i] = siF; lso[i] = soF;
    }
    __syncthreads();

    if (t < Dd) {
        int d = t; float aK = 0.f, aQ = 0.f;
        for (int i = 0; i < C; i++) {
            aK += skT[d * SRT + i] * lso[i];
            aQ += sqT[d * SRT + i] * lsi[i];
        }
        SKso[b * Dd + d] = aK;
        SQsi[b * Dd + d] = aQ;
    }
}

// K5: matmul-form pass2 (weighted causal sums), emits sal, e, chunk-local cumsum+total.
__global__ __launch_bounds__(256) void k_pass2mm(const float* __restrict__ Q,
                                                 const float* __restrict__ K,
                                                 const float* __restrict__ SKso,
                                                 const float* __restrict__ SQsi,
                                                 const float* __restrict__ si,
                                                 const float* __restrict__ so,
                                                 float* __restrict__ sal,
                                                 float* __restrict__ ecs,
                                                 float* __restrict__ ecum,
                                                 float* __restrict__ Tcs) {
    __shared__ float sqT[Dd * SRT];
    __shared__ float skT[Dd * SRT];
    __shared__ float P[C * SRP];
    __shared__ float colK[C], colQ[C], pks[Dd], pqs[Dd], lsi[C], lso[C];
    int b = blockIdx.x, s = b / NC, c = b % NC;
    int n = s / Hh, h = s % Hh, t = threadIdx.x;

#pragma unroll
    for (int j = 0; j < 4; j++) {
        int flat = 4 * t + 1024 * j, i = flat >> 6, d0 = flat & 63;
        int id = gidx(n, c * C + i, h, d0);
        float4 q4 = *(const float4*)&Q[id];
        float4 k4 = *(const float4*)&K[id];
        sqT[(d0 + 0) * SRT + i] = sigf(q4.x);
        sqT[(d0 + 1) * SRT + i] = sigf(q4.y);
        sqT[(d0 + 2) * SRT + i] = sigf(q4.z);
        sqT[(d0 + 3) * SRT + i] = sigf(q4.w);
        skT[(d0 + 0) * SRT + i] = sigf(k4.x);
        skT[(d0 + 1) * SRT + i] = sigf(k4.y);
        skT[(d0 + 2) * SRT + i] = sigf(k4.z);
        skT[(d0 + 3) * SRT + i] = sigf(k4.w);
    }
    if (t < Dd) {
        pks[t] = SKso[b * Dd + t]; pqs[t] = SQsi[b * Dd + t];
        lsi[t] = si[s * Ll + c * C + t]; lso[t] = so[s * Ll + c * C + t];
    }
    __syncthreads();

    int tx = t & 15, ty = t >> 4, i0 = 4 * ty, j0 = 4 * tx;
    float acc[4][4] = {};
    for (int d = 0; d < Dd; d++) {
        float4 a = *(const float4*)&sqT[d * SRT + i0];
        float4 bb = *(const float4*)&skT[d * SRT + j0];
        float av[4] = {a.x, a.y, a.z, a.w}, bv[4] = {bb.x, bb.y, bb.z, bb.w};
#pragma unroll
        for (int r = 0; r < 4; r++)
#pragma unroll
            for (int cc = 0; cc < 4; cc++) acc[r][cc] += av[r] * bv[cc];
    }
#pragma unroll
    for (int r = 0; r < 4; r++)
#pragma unroll
        for (int cc = 0; cc < 4; cc++) P[(i0 + r) * SRP + (j0 + cc)] = acc[r][cc];
    __syncthreads();

    if (t < C) {
        float ck = 0.f, cq = 0.f;
        for (int d = 0; d < Dd; d++) { ck += skT[d * SRT + t]; cq += sqT[d * SRT + t]; }
        colK[t] = ck; colQ[t] = cq;
    }
    __syncthreads();

    if (t < C) {
        int i = t, l = c * C + i;
        float rw1 = 0.f, rw2 = 0.f;
        for (int j = 0; j <= i; j++) {
            rw1 += lso[j] * (P[i * SRP + j] + EPSF * colK[j]);
            rw2 += lsi[j] * (P[j * SRP + i] + EPSF * colQ[j]);
        }
        float b1 = 0.f, b2 = 0.f;
        for (int d = 0; d < Dd; d++) {
            b1 += (sqT[d * SRT + i] + EPSF) * (pks[d] + EPSF);
            b2 += (skT[d * SRT + i] + EPSF) * (pqs[d] + EPSF);
        }
        float nf = (float)(l + 1);
        float cs  = (b1 + rw1) / nf;
        float csr = (b2 + rw2) / nf;
        csr = fminf(fmaxf(csr, -1.f), 1.f);
        float e = expf(csr);
        sal[s * Ll + l] = 1.0f / (1.0f + expf(-cs));
        ecs[s * Ll + l] = e;
        // inclusive wave scan over the 64 lanes of wave 0
        float run = e;
#pragma unroll
        for (int off = 1; off < 64; off <<= 1) {
            float o = __shfl_up(run, off, 64);
            if (i >= off) run += o;
        }
        ecum[s * Ll + l] = run;
        if (i == 63) Tcs[b] = run;
    }
}

// K6: exclusive prefix of chunk totals of e.  grid=S, block=64 (thread 0 works)
__global__ void k_prefixT(const float* __restrict__ Tcs, float* __restrict__ Pcs) {
    int s = blockIdx.x;
    if (threadIdx.x == 0) {
        float r = 0.f;
        for (int c = 0; c < NC; c++) {
            Pcs[s * NC + c] = r;
            r += Tcs[s * NC + c];
        }
    }
}

// K7: per-chunk KV sums: KV_c[d][m] = sum_l k[l][d] * (v[l][m]*scomp[l]).
__global__ __launch_bounds__(256) void k_chunkKV(const float* __restrict__ K,
                                                 const float* __restrict__ V,
                                                 const float* __restrict__ ecs,
                                                 const float* __restrict__ ecum,
                                                 const float* __restrict__ Pcs,
                                                 float* __restrict__ KV) {
    __shared__ float lk[C][Dd];
    __shared__ float lvs[C][Dd];
    __shared__ float lsc[C];
    int b = blockIdx.x, s = b / NC, c = b % NC;
    int n = s / Hh, h = s % Hh, t = threadIdx.x;
    if (t < C) {
        int l = c * C + t;
        lsc[t] = ecs[s * Ll + l] / (Pcs[b] + ecum[s * Ll + l]) * (float)(l + 1);
    }
    __syncthreads();
    for (int j = 0; j < C * Dd / 256; j++) {
        int flat = t + j * 256, i = flat >> 6, d = flat & 63;
        int l = c * C + i, id = gidx(n, l, h, d);
        lk[i][d]  = sigf(K[id]);
        lvs[i][d] = V[id] * lsc[i];
    }
    __syncthreads();
    int tx = t & 15, ty = t >> 4;
    int m0 = tx * 4, d0 = ty * 4;
    float acc[4][4] = {};
    for (int i = 0; i < C; i++) {
        float4 k4 = *(const float4*)&lk[i][d0];
        float4 v4 = *(const float4*)&lvs[i][m0];
        float kk[4] = {k4.x, k4.y, k4.z, k4.w};
        float vv[4] = {v4.x, v4.y, v4.z, v4.w};
#pragma unroll
        for (int r = 0; r < 4; r++)
#pragma unroll
            for (int cc = 0; cc < 4; cc++) acc[r][cc] += kk[r] * vv[cc];
    }
    float* dst = &KV[(size_t)b * Dd * Dd];
#pragma unroll
    for (int r = 0; r < 4; r++) {
        float4 o = {acc[r][0], acc[r][1], acc[r][2], acc[r][3]};
        *(float4*)&dst[(d0 + r) * Dd + m0] = o;
    }
}

// K8: in-place exclusive prefix of KV over chunks. grid=S*16, block=256
__global__ void k_prefixKV(float* __restrict__ KV) {
    int bx = blockIdx.x, s = bx >> 4, sub = bx & 15;
    int e0 = sub * 256 + threadIdx.x;
    float r = 0.f;
    for (int c = 0; c < NC; c++) {
        size_t a = (size_t)(s * NC + c) * (Dd * Dd) + e0;
        float t = KV[a];
        KV[a] = r;
        r += t;
    }
}

// K9: matmul-form final: out_i[m] = sir_i*sal_i*( sum_d sq_i[d]*KVp[d][m]
//                                  + sum_{j<=i} P[i][j]*vs_j[m] )
__global__ __launch_bounds__(256) void k_finalmm(const float* __restrict__ Q,
                                                 const float* __restrict__ K,
                                                 const float* __restrict__ V,
                                                 const float* __restrict__ si,
                                                 const float* __restrict__ sal,
                                                 const float* __restrict__ ecs,
                                                 const float* __restrict__ ecum,
                                                 const float* __restrict__ Pcs,
                                                 const float* __restrict__ KV,
                                                 float* __restrict__ Out) {
    __shared__ float sqT[Dd * SRT];   // sigmoid(q) transposed; later reused as masked-S^T
    __shared__ float skT[Dd * SRT];   // sigmoid(k) transposed; later reused as KVp
    __shared__ float vsm[C * SRT];    // vsm[j*SRT + m] = v_j[m]*scomp_j  (row-major)
    __shared__ float lsc[C], s2[C];
    int b = blockIdx.x, s = b / NC, c = b % NC;
    int n = s / Hh, h = s % Hh, t = threadIdx.x;

    if (t < C) {
        int l = c * C + t;
        lsc[t] = ecs[s * Ll + l] / (Pcs[b] + ecum[s * Ll + l]) * (float)(l + 1);
        s2[t]  = (si[s * Ll + l] / (float)(l + 1)) * sal[s * Ll + l];
    }
    __syncthreads();

#pragma unroll
    for (int j = 0; j < 4; j++) {
        int flat = 4 * t + 1024 * j, i = flat >> 6, d0 = flat & 63;
        int id = gidx(n, c * C + i, h, d0);
        float4 q4 = *(const float4*)&Q[id];
        float4 k4 = *(const float4*)&K[id];
        float4 v4 = *(const float4*)&V[id];
        sqT[(d0 + 0) * SRT + i] = sigf(q4.x);
        sqT[(d0 + 1) * SRT + i] = sigf(q4.y);
        sqT[(d0 + 2) * SRT + i] = sigf(q4.z);
        sqT[(d0 + 3) * SRT + i] = sigf(q4.w);
        skT[(d0 + 0) * SRT + i] = sigf(k4.x);
        skT[(d0 + 1) * SRT + i] = sigf(k4.y);
        skT[(d0 + 2) * SRT + i] = sigf(k4.z);
        skT[(d0 + 3) * SRT + i] = sigf(k4.w);
        float sc = lsc[i];
        float4 vv = {v4.x * sc, v4.y * sc, v4.z * sc, v4.w * sc};
        *(float4*)&vsm[i * SRT + d0] = vv;
    }
    __syncthreads();

    int tx = t & 15, ty = t >> 4, i0 = 4 * ty, m0 = 4 * tx;  // m0 doubles as j0 for P tiles

    // issue KV-prefix loads early (latency hidden behind P compute)
    float4 kv4[4];
#pragma unroll
    for (int j = 0; j < 4; j++) {
        int flat = 4 * t + 1024 * j, d = flat >> 6, mm = flat & 63;
        kv4[j] = *(const float4*)&KV[(size_t)b * (Dd * Dd) + d * Dd + mm];
    }

    // scores P[i0..+3][m0..+3]
    float p[4][4] = {};
    for (int d = 0; d < Dd; d++) {
        float4 a = *(const float4*)&sqT[d * SRT + i0];
        float4 bb = *(const float4*)&skT[d * SRT + m0];
        float av[4] = {a.x, a.y, a.z, a.w}, bv[4] = {bb.x, bb.y, bb.z, bb.w};
#pragma unroll
        for (int r = 0; r < 4; r++)
#pragma unroll
            for (int cc = 0; cc < 4; cc++) p[r][cc] += av[r] * bv[cc];
    }
    __syncthreads();   // all done reading skT

    // overwrite skT with KVp[d][m]
#pragma unroll
    for (int j = 0; j < 4; j++) {
        int flat = 4 * t + 1024 * j, d = flat >> 6, mm = flat & 63;
        *(float4*)&skT[d * SRT + mm] = kv4[j];
    }
    __syncthreads();

    // out tile: base matmul sqT^T x KVp
    float acc[4][4] = {};
    for (int d = 0; d < Dd; d++) {
        float4 a = *(const float4*)&sqT[d * SRT + i0];
        float4 bb = *(const float4*)&skT[d * SRT + m0];
        float av[4] = {a.x, a.y, a.z, a.w}, bv[4] = {bb.x, bb.y, bb.z, bb.w};
#pragma unroll
        for (int r = 0; r < 4; r++)
#pragma unroll
            for (int cc = 0; cc < 4; cc++) acc[r][cc] += av[r] * bv[cc];
    }
    __syncthreads();   // all done reading sqT

    // overwrite sqT with masked S^T: ST[j*SRT + i] = (j<=i) ? P[i][j] : 0
#pragma unroll
    for (int cc = 0; cc < 4; cc++) {
        int j = m0 + cc;
        float4 v;
        v.x = (j <= i0 + 0) ? p[0][cc] : 0.f;
        v.y = (j <= i0 + 1) ? p[1][cc] : 0.f;
        v.z = (j <= i0 + 2) ? p[2][cc] : 0.f;
        v.w = (j <= i0 + 3) ? p[3][cc] : 0.f;
        *(float4*)&sqT[j * SRT + i0] = v;
    }
    __syncthreads();

    // causal matmul: acc += ST^T x vs
    for (int j = 0; j < C; j++) {
        float4 a = *(const float4*)&sqT[j * SRT + i0];
        float4 bb = *(const float4*)&vsm[j * SRT + m0];
        float av[4] = {a.x, a.y, a.z, a.w}, bv[4] = {bb.x, bb.y, bb.z, bb.w};
#pragma unroll
        for (int r = 0; r < 4; r++)
#pragma unroll
            for (int cc = 0; cc < 4; cc++) acc[r][cc] += av[r] * bv[cc];
    }

#pragma unroll
    for (int r = 0; r < 4; r++) {
        int i = i0 + r, l = c * C + i;
        float sf = s2[i];
        float4 o = {acc[r][0] * sf, acc[r][1] * sf, acc[r][2] * sf, acc[r][3] * sf};
        *(float4*)&Out[gidx(n, l, h, m0)] = o;
    }
}

extern "C" void kernel_launch(void* const* d_in, const int* in_sizes, int n_in,
                              void* d_out, int out_size, void* d_ws, size_t ws_size,
                              hipStream_t stream) {
    const float* Q = (const float*)d_in[0];
    const float* K = (const float*)d_in[1];
    const float* V = (const float*)d_in[2];
    float* Out = (float*)d_out;

    float* ws   = (float*)d_ws;
    float* SK   = ws;                 // SC*Dd
    float* SQ   = SK   + SC * Dd;
    float* SKso = SQ   + SC * Dd;
    float* SQsi = SKso + SC * Dd;
    float* si   = SQsi + SC * Dd;     // S*Ll
    float* so   = si   + S * Ll;
    float* sal  = so   + S * Ll;
    float* ecs  = sal  + S * Ll;
    float* ecum = ecs  + S * Ll;
    float* Tcs  = ecum + S * Ll;      // SC
    float* Pcs  = Tcs  + SC;          // SC
    float* KV   = Pcs  + SC;          // SC*Dd*Dd

    k_chunksums<<<SC, 64, 0, stream>>>(Q, K, SK, SQ);
    k_prefixAB<<<S, 64, 0, stream>>>(SK, SQ);
    k_pass1mm<<<SC, 256, 0, stream>>>(Q, K, SK, SQ, SKso, SQsi, si, so);
    k_prefixAB<<<S, 64, 0, stream>>>(SKso, SQsi);
    k_pass2mm<<<SC, 256, 0, stream>>>(Q, K, SKso, SQsi, si, so, sal, ecs, ecum, Tcs);
    k_prefixT<<<S, 64, 0, stream>>>(Tcs, Pcs);
    k_chunkKV<<<SC, 256, 0, stream>>>(K, V, ecs, ecum, Pcs, KV);
    k_prefixKV<<<S * 16, 256, 0, stream>>>(KV);
    k_finalmm<<<SC, 256, 0, stream>>>(Q, K, V, si, sal, ecs, ecum, Pcs, KV, Out);
}